// Round 2
// baseline (478492.822 us; speedup 1.0000x reference)
//
#include <hip/hip_runtime.h>
#include <stdint.h>

typedef unsigned short u16;
typedef unsigned int   u32;

#define T_STEPS 4096
#define HID     1024
#define KXDIM   512
#define NBLK    256
#define TPB     256

// ---- LDS byte offsets ----
#define WG_OFF   0        // 16 cols x 1536 bf16 (3072B/col) = 48 KB
#define WHR_OFF  49152    // 4 cols x 64 chunks x 48B (16 bf16 used + pad) = 12 KB
#define WCR_OFF  61440    // 12 KB
#define ACT_OFF  73728    // 64 slices x 112B (24 floats + 16B pad) = 7 KB
#define HBUF_OFF 80896    // 64 chunks x 80B (16 floats + 16B pad) = 5 KB
#define CBUF_OFF 86016    // 5 KB
#define MISC_OFF 91136    // 64 floats: gact[16], u[4]@16, oloc[4]@20, cloc[4]@24, bg[16]@28, br[4]@44
#define SMEM_BYTES 91392

// ---- workspace u32 indices ----
#define CTRA_IDX 0        // 16 counters, 128B apart (u32 idx 0,32,...,480)
#define FLAG_IDX 500      // dtype flag: 0 = bf16 inputs, 1 = f32 inputs
#define CTRB_IDX 512      // 16 counters, 128B apart
#define GC_IDX   1024     // 1024 f32
#define GH_IDX   2048     // 1024 f32

__device__ __forceinline__ float bflo(u32 u){ union{u32 u; float f;} x; x.u = u << 16; return x.f; }
__device__ __forceinline__ float bfhi(u32 u){ union{u32 u; float f;} x; x.u = u & 0xffff0000u; return x.f; }
__device__ __forceinline__ float bfs(u16 v){ union{u32 u; float f;} x; x.u = ((u32)v) << 16; return x.f; }
__device__ __forceinline__ u16 f2b(float f){
  union{float f; u32 u;} x; x.f = f;
  u32 r = x.u + 0x7fffu + ((x.u >> 16) & 1u);
  return (u16)(r >> 16);
}

__device__ __forceinline__ float agent_ldf(const float* p){
  return __hip_atomic_load(p, __ATOMIC_RELAXED, __HIP_MEMORY_SCOPE_AGENT);
}
__device__ __forceinline__ void agent_stf(float* p, float v){
  __hip_atomic_store(p, v, __ATOMIC_RELAXED, __HIP_MEMORY_SCOPE_AGENT);
}

// arrive (release) + poll 16 spread counters (acquire) until sum >= target
__device__ __forceinline__ void gbar(u32* ctr, int slot, u32 target){
  __hip_atomic_fetch_add(ctr + slot * 32, 1u, __ATOMIC_RELEASE, __HIP_MEMORY_SCOPE_AGENT);
  for (;;){
    u32 s = 0;
#pragma unroll
    for (int i = 0; i < 16; ++i)
      s += __hip_atomic_load(ctr + i * 32, __ATOMIC_ACQUIRE, __HIP_MEMORY_SCOPE_AGENT);
    if (s >= target) return;
    __builtin_amdgcn_s_sleep(2);
  }
}

// dot of 16 fp32 activations (padded-chunk layout) with 16 bf16 weights (packed)
__device__ __forceinline__ float dot16(const float* av, const u32* wp){
  float hv[16];
  *(float4*)(hv + 0)  = *(const float4*)(av + 0);
  *(float4*)(hv + 4)  = *(const float4*)(av + 4);
  *(float4*)(hv + 8)  = *(const float4*)(av + 8);
  *(float4*)(hv + 12) = *(const float4*)(av + 12);
  u32 uu[8];
  *(uint4*)(uu + 0) = *(const uint4*)(wp + 0);
  *(uint4*)(uu + 4) = *(const uint4*)(wp + 4);
  float s = 0.f;
#pragma unroll
  for (int p = 0; p < 8; ++p){
    s = fmaf(hv[2*p],     bflo(uu[p]), s);
    s = fmaf(hv[2*p + 1], bfhi(uu[p]), s);
  }
  return s;
}

// weight fetch: f32 mode rounds (RNE) to bf16; bf16 mode passes through
__device__ __forceinline__ u16 ldw(const void* base, size_t idx, int f32m){
  return f32m ? f2b(((const float*)base)[idx]) : ((const u16*)base)[idx];
}

__global__ void __launch_bounds__(TPB) lstm_init(u32* ws){
  int i = blockIdx.x * blockDim.x + threadIdx.x;
  if (i < 3072)
    __hip_atomic_store(ws + i, 0u, __ATOMIC_RELAXED, __HIP_MEMORY_SCOPE_AGENT);
}

// dtype sniff: bf16 weights (|w| <= 2^-5) can never have a low-u16 bf16
// exponent field >= 144; f32 mantissa bits hit it with p~0.44 per sample.
__global__ void lstm_detect(const u32* __restrict__ wxg, u32* __restrict__ ws){
  if (threadIdx.x == 0 && blockIdx.x == 0){
    u32 f32m = 0;
    for (int i = 0; i < 128; ++i){
      u32 lo = wxg[i] & 0xffffu;
      u32 ef = (lo >> 7) & 0xffu;
      if (ef >= 144u) f32m = 1u;
    }
    __hip_atomic_store(ws + FLAG_IDX, f32m, __ATOMIC_RELAXED, __HIP_MEMORY_SCOPE_AGENT);
  }
}

__global__ void __launch_bounds__(TPB) lstm_persist(
    const void* __restrict__ x,   const void* __restrict__ Wxg,
    const void* __restrict__ Whg, const void* __restrict__ bg,
    const void* __restrict__ Wcr, const void* __restrict__ Whr,
    const void* __restrict__ br,  void* __restrict__ out,
    u32* __restrict__ ws)
{
  extern __shared__ char smem[];
  const int tid  = threadIdx.x;
  const int b    = blockIdx.x;
  const int j0   = b * 4;            // this block owns h/c indices j0..j0+3
  const int w    = tid >> 6;         // wave id 0..3
  const int lane = tid & 63;

  const int f32m = (int)ws[FLAG_IDX];   // written by lstm_detect (kernel-boundary coherent)

  u32*  ctrA = ws + CTRA_IDX;
  u32*  ctrB = ws + CTRB_IDX;
  float* g_c = (float*)(ws + GC_IDX);
  float* g_h = (float*)(ws + GH_IDX);

  u16*   wg   = (u16*)(smem + WG_OFF);
  u16*   whr  = (u16*)(smem + WHR_OFF);
  u16*   wcr  = (u16*)(smem + WCR_OFF);
  float* act  = (float*)(smem + ACT_OFF);
  float* hbuf = (float*)(smem + HBUF_OFF);
  float* cbuf = (float*)(smem + CBUF_OFF);
  float* misc = (float*)(smem + MISC_OFF);

  // ---------- one-time weight staging into LDS ----------
  {
    // gate columns: col c in [0,16): type=c>>2 (o,f,i,g), jl=c&3
    int c = tid >> 4, sub = tid & 15;
    int ty = c >> 2, jl = c & 3;
    size_t gcol = (size_t)(ty * HID + j0 + jl);
    u16* dst = wg + c * 1536;
    for (int k = sub * 96; k < sub * 96 + 96; ++k){
      u16 v = (k < KXDIM) ? ldw(Wxg, (size_t)k * 4096 + gcol, f32m)
                          : ldw(Whg, (size_t)(k - KXDIM) * 4096 + gcol, f32m);
      dst[k] = v;
    }
  }
  {
    // W_hr / W_cr columns, padded-chunk layout (24 u16 per 16 used)
    int jl = tid >> 6, sub = tid & 63;
    size_t j = (size_t)(j0 + jl);
    u16* dH = whr + jl * 1536 + sub * 24;
    u16* dC = wcr + jl * 1536 + sub * 24;
    for (int p = 0; p < 16; ++p){
      size_t k = (size_t)(sub * 16 + p);
      dH[p] = ldw(Whr, k * HID + j, f32m);
      dC[p] = ldw(Wcr, k * HID + j, f32m);
    }
  }
  if (tid < 16){
    size_t idx = (size_t)((tid >> 2) * HID + j0 + (tid & 3));
    misc[28 + tid] = f32m ? ((const float*)bg)[idx] : bfs(((const u16*)bg)[idx]);
  }
  if (tid < 4){
    size_t idx = (size_t)(j0 + tid);
    misc[44 + tid] = f32m ? ((const float*)br)[idx] : bfs(((const u16*)br)[idx]);
    misc[24 + tid] = 0.0f;    // c state
  }
  __syncthreads();

  for (int t = 0; t < T_STEPS; ++t){
    // ---------- stage x_t and h_t into LDS ----------
    {
      int e = tid * 2;                       // 0..510
      float f0, f1;
      if (f32m){
        const float* xr = (const float*)x + (size_t)t * KXDIM;
        f0 = xr[e]; f1 = xr[e + 1];
      } else {
        const u16* xr = (const u16*)x + (size_t)t * KXDIM;
        f0 = bfs(xr[e]); f1 = bfs(xr[e + 1]);
      }
      float* a = act + (e / 24) * 28 + (e % 24);
      a[0] = f0; a[1] = f1;
    }
    {
      int k = tid * 4;                       // 0..1020
      float h0 = agent_ldf(g_h + k + 0);
      float h1 = agent_ldf(g_h + k + 1);
      float h2 = agent_ldf(g_h + k + 2);
      float h3 = agent_ldf(g_h + k + 3);
      int e = KXDIM + k;
      float* a = act + (e / 24) * 28 + (e % 24);
      a[0] = h0; a[1] = h1; a[2] = h2; a[3] = h3;
      float* hb = hbuf + (k >> 4) * 20 + (k & 15);
      hb[0] = h0; hb[1] = h1; hb[2] = h2; hb[3] = h3;
    }
    __syncthreads();

    // ---------- u = h . W_hr (wave w -> jl=w), uses PREVIOUS h ----------
    {
      float ua = dot16(hbuf + lane * 20, (const u32*)(whr + w * 1536 + lane * 24));
#pragma unroll
      for (int m = 32; m >= 1; m >>= 1) ua += __shfl_xor(ua, m, 64);
      if (lane == 0) misc[16 + w] = ua;
    }

    // ---------- gates: wave w computes gate type w for jl=0..3 ----------
    {
      float a[24];
      const float* av = act + lane * 28;
#pragma unroll
      for (int i2 = 0; i2 < 6; ++i2)
        *(float4*)(a + 4 * i2) = *(const float4*)(av + 4 * i2);

      float acc[4];
#pragma unroll
      for (int c2 = 0; c2 < 4; ++c2){
        const u32* wp = (const u32*)(wg + (4 * w + c2) * 1536) + lane * 12;
        u32 uu[12];
        *(uint4*)(uu + 0) = *(const uint4*)(wp + 0);
        *(uint4*)(uu + 4) = *(const uint4*)(wp + 4);
        *(uint4*)(uu + 8) = *(const uint4*)(wp + 8);
        float s2 = 0.f, s3 = 0.f;
#pragma unroll
        for (int p = 0; p < 12; ++p){
          s2 = fmaf(a[2*p],     bflo(uu[p]), s2);
          s3 = fmaf(a[2*p + 1], bfhi(uu[p]), s3);
        }
        acc[c2] = s2 + s3;
      }
      // folded reduction: 2 butterfly levels on 4 accs, select, 4 more levels
#pragma unroll
      for (int c2 = 0; c2 < 4; ++c2){
        acc[c2] += __shfl_xor(acc[c2], 1, 64);
        acc[c2] += __shfl_xor(acc[c2], 2, 64);
      }
      float sel = (lane & 2) ? ((lane & 1) ? acc[3] : acc[2])
                             : ((lane & 1) ? acc[1] : acc[0]);
#pragma unroll
      for (int m = 4; m <= 32; m <<= 1) sel += __shfl_xor(sel, m, 64);
      if (lane < 4){
        float gv = sel + misc[28 + 4 * w + lane];
        gv = (w < 3) ? (1.0f / (1.0f + __expf(-gv))) : tanhf(gv);
        misc[4 * w + lane] = gv;   // gact[type=w][jl=lane]
      }
    }
    __syncthreads();

    // ---------- elementwise c update + broadcast c ----------
    if (tid < 4){
      float o  = misc[tid];
      float ff = misc[4 + tid];
      float ii = misc[8 + tid];
      float gg = misc[12 + tid];
      float cn = fmaf(ff, misc[24 + tid], ii * gg);
      misc[24 + tid] = cn;          // c state
      misc[20 + tid] = o;           // o for stage B
      agent_stf(g_c + j0 + tid, cn);
    }
    __syncthreads();
    if (tid == 0) gbar(ctrA, b & 15, (u32)(t + 1) * NBLK);
    __syncthreads();

    // ---------- fetch full c_new ----------
    {
      int k = tid * 4;
      float c0 = agent_ldf(g_c + k + 0);
      float c1 = agent_ldf(g_c + k + 1);
      float c2 = agent_ldf(g_c + k + 2);
      float c3 = agent_ldf(g_c + k + 3);
      float* cb = cbuf + (k >> 4) * 20 + (k & 15);
      cb[0] = c0; cb[1] = c1; cb[2] = c2; cb[3] = c3;
    }
    __syncthreads();

    // ---------- stage B: r = u + c_new.W_cr + b_r ; h_new = o*tanh(r) ----------
    {
      float ra = dot16(cbuf + lane * 20, (const u32*)(wcr + w * 1536 + lane * 24));
#pragma unroll
      for (int m = 32; m >= 1; m >>= 1) ra += __shfl_xor(ra, m, 64);
      if (lane == 0){
        float r  = misc[16 + w] + ra + misc[44 + w];
        float hn = misc[20 + w] * tanhf(r);
        if (f32m) ((float*)out)[(size_t)t * HID + j0 + w] = hn;
        else      ((u16*)out)[(size_t)t * HID + j0 + w] = f2b(hn);
        agent_stf(g_h + j0 + w, hn);
      }
    }
    __syncthreads();
    if (tid == 0) gbar(ctrB, b & 15, (u32)(t + 1) * NBLK);
    __syncthreads();
  }
}

extern "C" void kernel_launch(void* const* d_in, const int* in_sizes, int n_in,
                              void* d_out, int out_size, void* d_ws, size_t ws_size,
                              hipStream_t stream)
{
  const void* x   = d_in[0];
  const void* Wxg = d_in[1];
  const void* Whg = d_in[2];
  const void* bg  = d_in[3];
  const void* Wcr = d_in[4];   // NOTE: W_cr precedes W_hr in input order
  const void* Whr = d_in[5];
  const void* br  = d_in[6];
  u32* ws  = (u32*)d_ws;

  (void)in_sizes; (void)n_in; (void)out_size; (void)ws_size;

  lstm_init<<<dim3(12), dim3(256), 0, stream>>>(ws);
  lstm_detect<<<dim3(1), dim3(64), 0, stream>>>((const u32*)Wxg, ws);

  hipFuncSetAttribute((const void*)lstm_persist,
                      hipFuncAttributeMaxDynamicSharedMemorySize, SMEM_BYTES);
  lstm_persist<<<dim3(NBLK), dim3(TPB), SMEM_BYTES, stream>>>(
      x, Wxg, Whg, bg, Wcr, Whr, br, d_out, ws);
}

// Round 3
// 20755.377 us; speedup vs baseline: 23.0539x; 23.0539x over previous
//
#include <hip/hip_runtime.h>
#include <stdint.h>

typedef unsigned short u16;
typedef unsigned int   u32;
typedef unsigned long long u64;

#define T_STEPS 4096
#define HID     1024
#define KXDIM   512
#define NBLK    256
#define TPB     256

// ---- LDS byte offsets ----
#define WG_OFF   0        // 16 cols x 1536 bf16 (3072B/col) = 48 KB
#define WHR_OFF  49152    // 4 cols x 64 chunks x 48B (16 bf16 used + pad) = 12 KB
#define WCR_OFF  61440    // 12 KB
#define ACT_OFF  73728    // 64 slices x 112B (24 floats + 16B pad) = 7 KB
#define HBUF_OFF 80896    // 64 chunks x 80B (16 floats + 16B pad) = 5 KB
#define CBUF_OFF 86016    // 5 KB
#define MISC_OFF 91136    // 64 floats: gact[16], u[4]@16, oloc[4]@20, cloc[4]@24, bg[16]@28, br[4]@44
#define SMEM_BYTES 91392

// ---- workspace u32 indices ----
#define FLAG_IDX 0        // dtype flag: 0 = bf16 inputs, 1 = f32 inputs
#define GHP_IDX  512      // 1024 pairs {f32 val, u32 tag} = 2048 u32 (16B-aligned)
#define GCP_IDX  3072     // 1024 pairs
#define WS_INIT_U32 5120

__device__ __forceinline__ float bflo(u32 u){ union{u32 u; float f;} x; x.u = u << 16; return x.f; }
__device__ __forceinline__ float bfhi(u32 u){ union{u32 u; float f;} x; x.u = u & 0xffff0000u; return x.f; }
__device__ __forceinline__ float bfs(u16 v){ union{u32 u; float f;} x; x.u = ((u32)v) << 16; return x.f; }
__device__ __forceinline__ u16 f2b(float f){
  union{float f; u32 u;} x; x.f = f;
  u32 r = x.u + 0x7fffu + ((x.u >> 16) & 1u);
  return (u16)(r >> 16);
}

// ---- MALL-coherent (cross-XCD) tagged-pair exchange ----
// Pair k lives at base + 2k: [2k]=value bits, [2k+1]=step tag.
// sc0 sc1 => bypass L1/L2, served by MALL (device coherence point).
// 8B pairs are naturally atomic; the payload is its own ready-flag, so no
// barrier / fence / atomic RMW is needed anywhere in the hot loop.

__device__ __forceinline__ void st_pair(u32* base, int k, float val, u32 tag){
  union{float f; u32 u;} x; x.f = val;
  u64 d = ((u64)tag << 32) | (u64)x.u;
  asm volatile("global_store_dwordx2 %0, %1, off sc0 sc1"
               :: "v"(base + 2 * k), "v"(d) : "memory");
}

// poll 4 consecutive pairs (k0..k0+3, k0 % 4 == 0) until all tags == exp
__device__ __forceinline__ void poll4(const u32* base, int k0, u32 exp, float* v){
  const u32* p0 = base + 2 * k0;
  const u32* p1 = p0 + 4;
  uint4 a0, a1;
  for (;;){
    asm volatile("global_load_dwordx4 %0, %2, off sc0 sc1\n\t"
                 "global_load_dwordx4 %1, %3, off sc0 sc1\n\t"
                 "s_waitcnt vmcnt(0)"
                 : "=&v"(a0), "=&v"(a1) : "v"(p0), "v"(p1) : "memory");
    if (a0.y == exp && a0.w == exp && a1.y == exp && a1.w == exp) break;
    __builtin_amdgcn_s_sleep(4);
  }
  union{u32 u; float f;} c0, c1, c2, c3;
  c0.u = a0.x; c1.u = a0.z; c2.u = a1.x; c3.u = a1.z;
  v[0] = c0.f; v[1] = c1.f; v[2] = c2.f; v[3] = c3.f;
}

// dot of 16 fp32 activations (padded-chunk layout) with 16 bf16 weights (packed)
__device__ __forceinline__ float dot16(const float* av, const u32* wp){
  float hv[16];
  *(float4*)(hv + 0)  = *(const float4*)(av + 0);
  *(float4*)(hv + 4)  = *(const float4*)(av + 4);
  *(float4*)(hv + 8)  = *(const float4*)(av + 8);
  *(float4*)(hv + 12) = *(const float4*)(av + 12);
  u32 uu[8];
  *(uint4*)(uu + 0) = *(const uint4*)(wp + 0);
  *(uint4*)(uu + 4) = *(const uint4*)(wp + 4);
  float s = 0.f;
#pragma unroll
  for (int p = 0; p < 8; ++p){
    s = fmaf(hv[2*p],     bflo(uu[p]), s);
    s = fmaf(hv[2*p + 1], bfhi(uu[p]), s);
  }
  return s;
}

// weight fetch: f32 mode rounds (RNE) to bf16; bf16 mode passes through
__device__ __forceinline__ u16 ldw(const void* base, size_t idx, int f32m){
  return f32m ? f2b(((const float*)base)[idx]) : ((const u16*)base)[idx];
}

__global__ void __launch_bounds__(TPB) lstm_init(u32* ws){
  int i = blockIdx.x * blockDim.x + threadIdx.x;
  if (i < WS_INIT_U32) ws[i] = 0u;   // zero flag + h/c pair arrays (val=0, tag=0)
}

// dtype sniff: bf16 weights (|w| <= 2^-5) can never have a low-u16 bf16
// exponent field >= 144; f32 mantissa bits hit it with p~0.44 per sample.
__global__ void lstm_detect(const u32* __restrict__ wxg, u32* __restrict__ ws){
  if (threadIdx.x == 0 && blockIdx.x == 0){
    u32 f32m = 0;
    for (int i = 0; i < 128; ++i){
      u32 lo = wxg[i] & 0xffffu;
      u32 ef = (lo >> 7) & 0xffu;
      if (ef >= 144u) f32m = 1u;
    }
    ws[FLAG_IDX] = f32m;
  }
}

__global__ void __launch_bounds__(TPB) lstm_persist(
    const void* __restrict__ x,   const void* __restrict__ Wxg,
    const void* __restrict__ Whg, const void* __restrict__ bg,
    const void* __restrict__ Wcr, const void* __restrict__ Whr,
    const void* __restrict__ br,  void* __restrict__ out,
    u32* __restrict__ ws)
{
  extern __shared__ char smem[];
  const int tid  = threadIdx.x;
  const int b    = blockIdx.x;
  const int j0   = b * 4;            // this block owns h/c indices j0..j0+3
  const int w    = tid >> 6;         // wave id 0..3
  const int lane = tid & 63;

  const int f32m = (int)ws[FLAG_IDX];   // written by lstm_detect (kernel-boundary coherent)

  u32* ghp = ws + GHP_IDX;
  u32* gcp = ws + GCP_IDX;

  u16*   wg   = (u16*)(smem + WG_OFF);
  u16*   whr  = (u16*)(smem + WHR_OFF);
  u16*   wcr  = (u16*)(smem + WCR_OFF);
  float* act  = (float*)(smem + ACT_OFF);
  float* hbuf = (float*)(smem + HBUF_OFF);
  float* cbuf = (float*)(smem + CBUF_OFF);
  float* misc = (float*)(smem + MISC_OFF);

  // ---------- one-time weight staging into LDS ----------
  {
    // gate columns: col c in [0,16): type=c>>2 (o,f,i,g), jl=c&3
    int c = tid >> 4, sub = tid & 15;
    int ty = c >> 2, jl = c & 3;
    size_t gcol = (size_t)(ty * HID + j0 + jl);
    u16* dst = wg + c * 1536;
    for (int k = sub * 96; k < sub * 96 + 96; ++k){
      u16 v = (k < KXDIM) ? ldw(Wxg, (size_t)k * 4096 + gcol, f32m)
                          : ldw(Whg, (size_t)(k - KXDIM) * 4096 + gcol, f32m);
      dst[k] = v;
    }
  }
  {
    // W_hr / W_cr columns, padded-chunk layout (24 u16 per 16 used)
    int jl = tid >> 6, sub = tid & 63;
    size_t j = (size_t)(j0 + jl);
    u16* dH = whr + jl * 1536 + sub * 24;
    u16* dC = wcr + jl * 1536 + sub * 24;
    for (int p = 0; p < 16; ++p){
      size_t k = (size_t)(sub * 16 + p);
      dH[p] = ldw(Whr, k * HID + j, f32m);
      dC[p] = ldw(Wcr, k * HID + j, f32m);
    }
  }
  if (tid < 16){
    size_t idx = (size_t)((tid >> 2) * HID + j0 + (tid & 3));
    misc[28 + tid] = f32m ? ((const float*)bg)[idx] : bfs(((const u16*)bg)[idx]);
  }
  if (tid < 4){
    size_t idx = (size_t)(j0 + tid);
    misc[44 + tid] = f32m ? ((const float*)br)[idx] : bfs(((const u16*)br)[idx]);
    misc[24 + tid] = 0.0f;    // c state
  }
  __syncthreads();

  for (int t = 0; t < T_STEPS; ++t){
    // ---------- stage x_t into LDS ----------
    {
      int e = tid * 2;                       // 0..510
      float f0, f1;
      if (f32m){
        const float* xr = (const float*)x + (size_t)t * KXDIM;
        f0 = xr[e]; f1 = xr[e + 1];
      } else {
        const u16* xr = (const u16*)x + (size_t)t * KXDIM;
        f0 = bfs(xr[e]); f1 = bfs(xr[e + 1]);
      }
      float* a = act + (e / 24) * 28 + (e % 24);
      a[0] = f0; a[1] = f1;
    }
    // ---------- h exchange: poll tagged pairs (tag == t), stage into LDS ----------
    {
      int k = tid * 4;                       // 0..1020
      float hv[4];
      poll4(ghp, k, (u32)t, hv);
      int e = KXDIM + k;
      float* a = act + (e / 24) * 28 + (e % 24);
      a[0] = hv[0]; a[1] = hv[1]; a[2] = hv[2]; a[3] = hv[3];
      float* hb = hbuf + (k >> 4) * 20 + (k & 15);
      hb[0] = hv[0]; hb[1] = hv[1]; hb[2] = hv[2]; hb[3] = hv[3];
    }
    __syncthreads();

    // ---------- u = h . W_hr (wave w -> jl=w), uses PREVIOUS h ----------
    {
      float ua = dot16(hbuf + lane * 20, (const u32*)(whr + w * 1536 + lane * 24));
#pragma unroll
      for (int m = 32; m >= 1; m >>= 1) ua += __shfl_xor(ua, m, 64);
      if (lane == 0) misc[16 + w] = ua;
    }

    // ---------- gates: wave w computes gate type w for jl=0..3 ----------
    {
      float a[24];
      const float* av = act + lane * 28;
#pragma unroll
      for (int i2 = 0; i2 < 6; ++i2)
        *(float4*)(a + 4 * i2) = *(const float4*)(av + 4 * i2);

      float acc[4];
#pragma unroll
      for (int c2 = 0; c2 < 4; ++c2){
        const u32* wp = (const u32*)(wg + (4 * w + c2) * 1536) + lane * 12;
        u32 uu[12];
        *(uint4*)(uu + 0) = *(const uint4*)(wp + 0);
        *(uint4*)(uu + 4) = *(const uint4*)(wp + 4);
        *(uint4*)(uu + 8) = *(const uint4*)(wp + 8);
        float s2 = 0.f, s3 = 0.f;
#pragma unroll
        for (int p = 0; p < 12; ++p){
          s2 = fmaf(a[2*p],     bflo(uu[p]), s2);
          s3 = fmaf(a[2*p + 1], bfhi(uu[p]), s3);
        }
        acc[c2] = s2 + s3;
      }
      // folded reduction: 2 butterfly levels on 4 accs, select, 4 more levels
#pragma unroll
      for (int c2 = 0; c2 < 4; ++c2){
        acc[c2] += __shfl_xor(acc[c2], 1, 64);
        acc[c2] += __shfl_xor(acc[c2], 2, 64);
      }
      float sel = (lane & 2) ? ((lane & 1) ? acc[3] : acc[2])
                             : ((lane & 1) ? acc[1] : acc[0]);
#pragma unroll
      for (int m = 4; m <= 32; m <<= 1) sel += __shfl_xor(sel, m, 64);
      if (lane < 4){
        float gv = sel + misc[28 + 4 * w + lane];
        gv = (w < 3) ? (1.0f / (1.0f + __expf(-gv))) : tanhf(gv);
        misc[4 * w + lane] = gv;   // gact[type=w][jl=lane]
      }
    }
    __syncthreads();

    // ---------- elementwise c update + publish tagged c (tag = t+1) ----------
    if (tid < 4){
      float o  = misc[tid];
      float ff = misc[4 + tid];
      float ii = misc[8 + tid];
      float gg = misc[12 + tid];
      float cn = fmaf(ff, misc[24 + tid], ii * gg);
      misc[24 + tid] = cn;          // c state
      misc[20 + tid] = o;           // o for stage B
      st_pair(gcp, j0 + tid, cn, (u32)(t + 1));
    }
    // ---------- c exchange: poll tagged pairs (tag == t+1) ----------
    {
      int k = tid * 4;
      float cv[4];
      poll4(gcp, k, (u32)(t + 1), cv);
      float* cb = cbuf + (k >> 4) * 20 + (k & 15);
      cb[0] = cv[0]; cb[1] = cv[1]; cb[2] = cv[2]; cb[3] = cv[3];
    }
    __syncthreads();

    // ---------- stage B: r = u + c_new.W_cr + b_r ; h_new = o*tanh(r) ----------
    {
      float ra = dot16(cbuf + lane * 20, (const u32*)(wcr + w * 1536 + lane * 24));
#pragma unroll
      for (int m = 32; m >= 1; m >>= 1) ra += __shfl_xor(ra, m, 64);
      if (lane == 0){
        float r  = misc[16 + w] + ra + misc[44 + w];
        float hn = misc[20 + w] * tanhf(r);
        if (f32m) ((float*)out)[(size_t)t * HID + j0 + w] = hn;
        else      ((u16*)out)[(size_t)t * HID + j0 + w] = f2b(hn);
        st_pair(ghp, j0 + w, hn, (u32)(t + 1));   // publish tagged h
      }
    }
    // no trailing barrier: next iteration's staging touches only act/hbuf,
    // which stage B never reads; the post-staging __syncthreads re-converges.
  }
}

extern "C" void kernel_launch(void* const* d_in, const int* in_sizes, int n_in,
                              void* d_out, int out_size, void* d_ws, size_t ws_size,
                              hipStream_t stream)
{
  const void* x   = d_in[0];
  const void* Wxg = d_in[1];
  const void* Whg = d_in[2];
  const void* bg  = d_in[3];
  const void* Wcr = d_in[4];   // NOTE: W_cr precedes W_hr in input order
  const void* Whr = d_in[5];
  const void* br  = d_in[6];
  u32* ws  = (u32*)d_ws;

  (void)in_sizes; (void)n_in; (void)out_size; (void)ws_size;

  lstm_init<<<dim3(20), dim3(256), 0, stream>>>(ws);
  lstm_detect<<<dim3(1), dim3(64), 0, stream>>>((const u32*)Wxg, ws);

  hipFuncSetAttribute((const void*)lstm_persist,
                      hipFuncAttributeMaxDynamicSharedMemorySize, SMEM_BYTES);
  lstm_persist<<<dim3(NBLK), dim3(TPB), SMEM_BYTES, stream>>>(
      x, Wxg, Whg, bg, Wcr, Whr, br, d_out, ws);
}

// Round 5
// 18249.347 us; speedup vs baseline: 26.2197x; 1.1373x over previous
//
#include <hip/hip_runtime.h>
#include <stdint.h>

typedef unsigned short u16;
typedef unsigned int   u32;
typedef unsigned long long u64;

#define T_STEPS 4096
#define HID     1024
#define KXDIM   512
#define NBLK    256
#define TPB     256
#define NREP    4          // replicas of published h/c pair arrays (reader fan-in / 4)

// ---- LDS byte offsets ----
#define WG_OFF   0        // 16 cols x 1536 bf16 (3072B/col) = 48 KB ; col c: ty=c>>2, jl=c&3
#define WHR_OFF  49152    // 4 cols x 64 chunks x 48B (16 bf16 used + pad) = 12 KB
#define WCR_OFF  61440    // 12 KB
#define ACT_OFF  73728    // 64 slices x 112B (24 floats + 16B pad) = 7 KB
#define HBUF_OFF 80896    // 64 chunks x 80B (16 floats + 16B pad) = 5 KB
#define CBUF_OFF 86016    // 5 KB
#define MISC_OFF 91136    // 64 floats: gact[16], u[4]@16, oloc[4]@20, cloc[4]@24, bg[16]@28, br[4]@44
#define SMEM_BYTES 91392

// ---- workspace u32 indices ----
#define FLAG_IDX 0        // dtype flag: 0 = bf16 inputs, 1 = f32 inputs
#define GHP_IDX  512                    // NREP replicas x 2048 u32 (1024 pairs each)
#define GCP_IDX  (512 + NREP * 2048)
#define WS_INIT_U32 (512 + 2 * NREP * 2048)

__device__ __forceinline__ float bflo(u32 u){ union{u32 u; float f;} x; x.u = u << 16; return x.f; }
__device__ __forceinline__ float bfhi(u32 u){ union{u32 u; float f;} x; x.u = u & 0xffff0000u; return x.f; }
__device__ __forceinline__ float bfs(u16 v){ union{u32 u; float f;} x; x.u = ((u32)v) << 16; return x.f; }
__device__ __forceinline__ float asf(u32 u){ union{u32 u; float f;} x; x.u = u; return x.f; }
__device__ __forceinline__ u16 f2b(float f){
  union{float f; u32 u;} x; x.f = f;
  u32 r = x.u + 0x7fffu + ((x.u >> 16) & 1u);
  return (u16)(r >> 16);
}

// ---- MALL-coherent tagged-pair exchange (sc0 sc1 = bypass L1/L2, served at
// the device coherence point). Pair k at base+2k: [0]=value bits, [1]=tag.
// 8B store is naturally atomic: payload is its own ready-flag.

__device__ __forceinline__ void st_pair(u32* base, int k, float val, u32 tag){
  union{float f; u32 u;} x; x.f = val;
  u64 d = ((u64)tag << 32) | (u64)x.u;
  asm volatile("global_store_dwordx2 %0, %1, off sc0 sc1"
               :: "v"(base + 2 * k), "v"(d) : "memory");
}

// poll 4 consecutive pairs until all tags == exp; tight loop, late backoff
__device__ __forceinline__ void poll4(const u32* base, int k0, u32 exp, float* v){
  const u32* p0 = base + 2 * k0;
  const u32* p1 = p0 + 4;
  uint4 a0, a1;
  int tries = 0;
  for (;;){
    asm volatile("global_load_dwordx4 %0, %2, off sc0 sc1\n\t"
                 "global_load_dwordx4 %1, %3, off sc0 sc1\n\t"
                 "s_waitcnt vmcnt(0)"
                 : "=&v"(a0), "=&v"(a1) : "v"(p0), "v"(p1) : "memory");
    if (a0.y == exp && a0.w == exp && a1.y == exp && a1.w == exp) break;
    if (++tries > 48) __builtin_amdgcn_s_sleep(8);
  }
  v[0] = asf(a0.x); v[1] = asf(a0.z); v[2] = asf(a1.x); v[3] = asf(a1.z);
}

// dot of 16 fp32 activations (padded-chunk layout) with 16 bf16 weights (packed)
__device__ __forceinline__ float dot16(const float* av, const u32* wp){
  float hv[16];
  *(float4*)(hv + 0)  = *(const float4*)(av + 0);
  *(float4*)(hv + 4)  = *(const float4*)(av + 4);
  *(float4*)(hv + 8)  = *(const float4*)(av + 8);
  *(float4*)(hv + 12) = *(const float4*)(av + 12);
  u32 uu[8];
  *(uint4*)(uu + 0) = *(const uint4*)(wp + 0);
  *(uint4*)(uu + 4) = *(const uint4*)(wp + 4);
  float s = 0.f;
#pragma unroll
  for (int p = 0; p < 8; ++p){
    s = fmaf(hv[2*p],     bflo(uu[p]), s);
    s = fmaf(hv[2*p + 1], bfhi(uu[p]), s);
  }
  return s;
}

// weight fetch: f32 mode rounds (RNE) to bf16; bf16 mode passes through
__device__ __forceinline__ u16 ldw(const void* base, size_t idx, int f32m){
  return f32m ? f2b(((const float*)base)[idx]) : ((const u16*)base)[idx];
}

__global__ void __launch_bounds__(TPB) lstm_init(u32* ws){
  int i = blockIdx.x * blockDim.x + threadIdx.x;
  if (i < WS_INIT_U32) ws[i] = 0u;   // zero flag + replica pair arrays (val=0, tag=0)
}

// dtype sniff: bf16 weights (|w| <= 2^-5) can never have a low-u16 bf16
// exponent field >= 144; f32 mantissa bits hit it with p~0.44 per sample.
__global__ void lstm_detect(const u32* __restrict__ wxg, u32* __restrict__ ws){
  if (threadIdx.x == 0 && blockIdx.x == 0){
    u32 f32m = 0;
    for (int i = 0; i < 128; ++i){
      u32 lo = wxg[i] & 0xffffu;
      u32 ef = (lo >> 7) & 0xffu;
      if (ef >= 144u) f32m = 1u;
    }
    ws[FLAG_IDX] = f32m;
  }
}

__global__ void __launch_bounds__(TPB) lstm_persist(
    const void* __restrict__ x,   const void* __restrict__ Wxg,
    const void* __restrict__ Whg, const void* __restrict__ bg,
    const void* __restrict__ Wcr, const void* __restrict__ Whr,
    const void* __restrict__ br,  void* __restrict__ out,
    u32* __restrict__ ws)
{
  extern __shared__ char smem[];
  const int tid  = threadIdx.x;
  const int b    = blockIdx.x;
  const int j0   = b * 4;            // this block owns h/c indices j0..j0+3
  const int w    = tid >> 6;         // wave id 0..3
  const int lane = tid & 63;

  const int f32m = (int)ws[FLAG_IDX];   // written by lstm_detect (kernel-boundary coherent)

  u32* ghp = ws + GHP_IDX;           // + r*2048 per replica
  u32* gcp = ws + GCP_IDX;
  u32* ghp_rd = ghp + (b & (NREP - 1)) * 2048;
  u32* gcp_rd = gcp + (b & (NREP - 1)) * 2048;

  u16*   wg   = (u16*)(smem + WG_OFF);
  u16*   whr  = (u16*)(smem + WHR_OFF);
  u16*   wcr  = (u16*)(smem + WCR_OFF);
  float* act  = (float*)(smem + ACT_OFF);
  float* hbuf = (float*)(smem + HBUF_OFF);
  float* cbuf = (float*)(smem + CBUF_OFF);
  float* misc = (float*)(smem + MISC_OFF);

  // ---------- one-time weight staging into LDS ----------
  {
    // gate columns: col c in [0,16): type=c>>2 (o,f,i,g), jl=c&3
    int c = tid >> 4, sub = tid & 15;
    int ty = c >> 2, jl = c & 3;
    size_t gcol = (size_t)(ty * HID + j0 + jl);
    u16* dst = wg + c * 1536;
    for (int k = sub * 96; k < sub * 96 + 96; ++k){
      u16 v = (k < KXDIM) ? ldw(Wxg, (size_t)k * 4096 + gcol, f32m)
                          : ldw(Whg, (size_t)(k - KXDIM) * 4096 + gcol, f32m);
      dst[k] = v;
    }
  }
  {
    // W_hr / W_cr columns, padded-chunk layout (24 u16 per 16 used)
    int jl = tid >> 6, sub = tid & 63;
    size_t j = (size_t)(j0 + jl);
    u16* dH = whr + jl * 1536 + sub * 24;
    u16* dC = wcr + jl * 1536 + sub * 24;
    for (int p = 0; p < 16; ++p){
      size_t k = (size_t)(sub * 16 + p);
      dH[p] = ldw(Whr, k * HID + j, f32m);
      dC[p] = ldw(Wcr, k * HID + j, f32m);
    }
  }
  if (tid < 16){
    size_t idx = (size_t)((tid >> 2) * HID + j0 + (tid & 3));
    misc[28 + tid] = f32m ? ((const float*)bg)[idx] : bfs(((const u16*)bg)[idx]);
  }
  if (tid < 4){
    size_t idx = (size_t)(j0 + tid);
    misc[44 + tid] = f32m ? ((const float*)br)[idx] : bfs(((const u16*)br)[idx]);
    misc[24 + tid] = 0.0f;    // c state
  }
  __syncthreads();

  for (int t = 0; t < T_STEPS; ++t){
    // ---------- stage x_t into LDS ----------
    {
      int e = tid * 2;                       // 0..510
      float f0, f1;
      if (f32m){
        const float* xr = (const float*)x + (size_t)t * KXDIM;
        f0 = xr[e]; f1 = xr[e + 1];
      } else {
        const u16* xr = (const u16*)x + (size_t)t * KXDIM;
        f0 = bfs(xr[e]); f1 = bfs(xr[e + 1]);
      }
      float* a = act + (e / 24) * 28 + (e % 24);
      a[0] = f0; a[1] = f1;
    }
    // ---------- h exchange: poll tagged pairs (tag == t), stage into LDS ----------
    {
      int k = tid * 4;                       // 0..1020
      float hv[4];
      poll4(ghp_rd, k, (u32)t, hv);
      int e = KXDIM + k;
      float* a = act + (e / 24) * 28 + (e % 24);
      a[0] = hv[0]; a[1] = hv[1]; a[2] = hv[2]; a[3] = hv[3];
      float* hb = hbuf + (k >> 4) * 20 + (k & 15);
      hb[0] = hv[0]; hb[1] = hv[1]; hb[2] = hv[2]; hb[3] = hv[3];
    }
    __syncthreads();

    // ---------- u = h . W_hr (wave w -> jl=w), uses PREVIOUS h ----------
    {
      float ua = dot16(hbuf + lane * 20, (const u32*)(whr + w * 1536 + lane * 24));
#pragma unroll
      for (int m = 32; m >= 1; m >>= 1) ua += __shfl_xor(ua, m, 64);
      if (lane == 0) misc[16 + w] = ua;
    }

    // ---------- gates: wave w computes gate type w for jl=0..3 ----------
    {
      float a[24];
      const float* av = act + lane * 28;
#pragma unroll
      for (int i2 = 0; i2 < 6; ++i2)
        *(float4*)(a + 4 * i2) = *(const float4*)(av + 4 * i2);

      float acc[4];
#pragma unroll
      for (int c2 = 0; c2 < 4; ++c2){
        const u32* wp = (const u32*)(wg + (4 * w + c2) * 1536) + lane * 12;
        u32 uu[12];
        *(uint4*)(uu + 0) = *(const uint4*)(wp + 0);
        *(uint4*)(uu + 4) = *(const uint4*)(wp + 4);
        *(uint4*)(uu + 8) = *(const uint4*)(wp + 8);
        float s2 = 0.f, s3 = 0.f;
#pragma unroll
        for (int p = 0; p < 12; ++p){
          s2 = fmaf(a[2*p],     bflo(uu[p]), s2);
          s3 = fmaf(a[2*p + 1], bfhi(uu[p]), s3);
        }
        acc[c2] = s2 + s3;
      }
      // folded reduction: 2 butterfly levels on 4 accs, select, 4 more levels
#pragma unroll
      for (int c2 = 0; c2 < 4; ++c2){
        acc[c2] += __shfl_xor(acc[c2], 1, 64);
        acc[c2] += __shfl_xor(acc[c2], 2, 64);
      }
      float sel = (lane & 2) ? ((lane & 1) ? acc[3] : acc[2])
                             : ((lane & 1) ? acc[1] : acc[0]);
#pragma unroll
      for (int m = 4; m <= 32; m <<= 1) sel += __shfl_xor(sel, m, 64);
      if (lane < 4){
        float gv = sel + misc[28 + 4 * w + lane];
        gv = (w < 3) ? (1.0f / (1.0f + __expf(-gv))) : tanhf(gv);
        misc[4 * w + lane] = gv;   // gact[type=w][jl=lane]
      }
    }
    __syncthreads();

    // ---------- elementwise c update + publish tagged c to all replicas ----------
    if (tid < 4){
      float o  = misc[tid];
      float ff = misc[4 + tid];
      float ii = misc[8 + tid];
      float gg = misc[12 + tid];
      float cn = fmaf(ff, misc[24 + tid], ii * gg);
      misc[24 + tid] = cn;          // c state
      misc[20 + tid] = o;           // o for stage B
#pragma unroll
      for (int rp = 0; rp < NREP; ++rp)
        st_pair(gcp + rp * 2048, j0 + tid, cn, (u32)(t + 1));
    }
    // ---------- c exchange: poll tagged pairs (tag == t+1) ----------
    {
      int k = tid * 4;
      float cv[4];
      poll4(gcp_rd, k, (u32)(t + 1), cv);
      float* cb = cbuf + (k >> 4) * 20 + (k & 15);
      cb[0] = cv[0]; cb[1] = cv[1]; cb[2] = cv[2]; cb[3] = cv[3];
    }
    __syncthreads();

    // ---------- stage B: r = u + c_new.W_cr + b_r ; h_new = o*tanh(r) ----------
    {
      float ra = dot16(cbuf + lane * 20, (const u32*)(wcr + w * 1536 + lane * 24));
#pragma unroll
      for (int m = 1; m <= 32; m <<= 1) ra += __shfl_xor(ra, m, 64);
      // all lanes hold full ra; misc reads broadcast -> hn is lane-uniform
      float r  = misc[16 + w] + ra + misc[44 + w];
      float hn = misc[20 + w] * tanhf(r);
      if (lane < 4) st_pair(ghp + lane * 2048, j0 + w, hn, (u32)(t + 1));
      if (lane == 4){
        if (f32m) ((float*)out)[(size_t)t * HID + j0 + w] = hn;
        else      ((u16*)out)[(size_t)t * HID + j0 + w] = f2b(hn);
      }
    }
    // no trailing barrier: next iteration's staging touches only act/hbuf,
    // which stage B never reads; the post-staging __syncthreads re-converges.
  }
}

extern "C" void kernel_launch(void* const* d_in, const int* in_sizes, int n_in,
                              void* d_out, int out_size, void* d_ws, size_t ws_size,
                              hipStream_t stream)
{
  const void* x   = d_in[0];
  const void* Wxg = d_in[1];
  const void* Whg = d_in[2];
  const void* bg  = d_in[3];
  const void* Wcr = d_in[4];   // NOTE: W_cr precedes W_hr in input order
  const void* Whr = d_in[5];
  const void* br  = d_in[6];
  u32* ws  = (u32*)d_ws;

  (void)in_sizes; (void)n_in; (void)out_size; (void)ws_size;

  lstm_init<<<dim3((WS_INIT_U32 + 255) / 256), dim3(256), 0, stream>>>(ws);
  lstm_detect<<<dim3(1), dim3(64), 0, stream>>>((const u32*)Wxg, ws);

  hipFuncSetAttribute((const void*)lstm_persist,
                      hipFuncAttributeMaxDynamicSharedMemorySize, SMEM_BYTES);
  lstm_persist<<<dim3(NBLK), dim3(TPB), SMEM_BYTES, stream>>>(
      x, Wxg, Whg, bg, Wcr, Whr, br, d_out, ws);
}

// Round 6
// 14316.356 us; speedup vs baseline: 33.4228x; 1.2747x over previous
//
#include <hip/hip_runtime.h>
#include <stdint.h>

typedef unsigned short u16;
typedef unsigned int   u32;
typedef unsigned long long u64;

#define T_STEPS 4096
#define HID     1024
#define KXDIM   512
#define NBLK    256
#define TPB     256
#define NREP    4          // replicas of published h/c pair arrays (reader fan-in / 4)

// ---- LDS byte offsets ----
// gate col c = w*4 + q : gate type q (0=o,1=f,2=i,3=g) of column j = j0 + w
#define WG_OFF   0        // 16 cols x 1536 bf16 (3072B/col) = 48 KB
#define WHR_OFF  49152    // 4 cols x 64 chunks x 48B (16 bf16 used + pad) = 12 KB
#define WCR_OFF  61440    // 12 KB
#define ACT_OFF  73728    // 64 slices x 112B (24 floats + 16B pad) = 7 KB
#define HBUF_OFF 80896    // 64 chunks x 80B (16 floats + 16B pad) = 5 KB
#define CBUF_OFF 86016    // 5 KB
#define SMEM_BYTES 91136

// ---- workspace u32 indices ----
#define FLAG_IDX 0        // dtype flag: 0 = bf16 inputs, 1 = f32 inputs
#define GHP_IDX  512                    // NREP replicas x 2048 u32 (1024 pairs each)
#define GCP_IDX  (512 + NREP * 2048)
#define WS_INIT_U32 (512 + 2 * NREP * 2048)

__device__ __forceinline__ float bflo(u32 u){ union{u32 u; float f;} x; x.u = u << 16; return x.f; }
__device__ __forceinline__ float bfhi(u32 u){ union{u32 u; float f;} x; x.u = u & 0xffff0000u; return x.f; }
__device__ __forceinline__ float bfs(u16 v){ union{u32 u; float f;} x; x.u = ((u32)v) << 16; return x.f; }
__device__ __forceinline__ float asf(u32 u){ union{u32 u; float f;} x; x.u = u; return x.f; }
__device__ __forceinline__ u16 f2b(float f){
  union{float f; u32 u;} x; x.f = f;
  u32 r = x.u + 0x7fffu + ((x.u >> 16) & 1u);
  return (u16)(r >> 16);
}

// ---- MALL-coherent tagged-pair exchange (sc0 sc1 = bypass L1/L2, served at
// the device coherence point). Pair k at base+2k: [0]=value bits, [1]=tag.
// 8B store is naturally atomic: payload is its own ready-flag.

__device__ __forceinline__ void st_pair(u32* base, int k, float val, u32 tag){
  union{float f; u32 u;} x; x.f = val;
  u64 d = ((u64)tag << 32) | (u64)x.u;
  asm volatile("global_store_dwordx2 %0, %1, off sc0 sc1"
               :: "v"(base + 2 * k), "v"(d) : "memory");
}

// poll 4 consecutive pairs until all tags == exp; tight loop, late backoff
__device__ __forceinline__ void poll4(const u32* base, int k0, u32 exp, float* v){
  const u32* p0 = base + 2 * k0;
  const u32* p1 = p0 + 4;
  uint4 a0, a1;
  int tries = 0;
  for (;;){
    asm volatile("global_load_dwordx4 %0, %2, off sc0 sc1\n\t"
                 "global_load_dwordx4 %1, %3, off sc0 sc1\n\t"
                 "s_waitcnt vmcnt(0)"
                 : "=&v"(a0), "=&v"(a1) : "v"(p0), "v"(p1) : "memory");
    if (a0.y == exp && a0.w == exp && a1.y == exp && a1.w == exp) break;
    if (++tries > 48) __builtin_amdgcn_s_sleep(8);
  }
  v[0] = asf(a0.x); v[1] = asf(a0.z); v[2] = asf(a1.x); v[3] = asf(a1.z);
}

// dot of 16 fp32 activations (padded-chunk layout) with 16 bf16 weights (packed)
__device__ __forceinline__ float dot16(const float* av, const u32* wp){
  float hv[16];
  *(float4*)(hv + 0)  = *(const float4*)(av + 0);
  *(float4*)(hv + 4)  = *(const float4*)(av + 4);
  *(float4*)(hv + 8)  = *(const float4*)(av + 8);
  *(float4*)(hv + 12) = *(const float4*)(av + 12);
  u32 uu[8];
  *(uint4*)(uu + 0) = *(const uint4*)(wp + 0);
  *(uint4*)(uu + 4) = *(const uint4*)(wp + 4);
  float s = 0.f;
#pragma unroll
  for (int p = 0; p < 8; ++p){
    s = fmaf(hv[2*p],     bflo(uu[p]), s);
    s = fmaf(hv[2*p + 1], bfhi(uu[p]), s);
  }
  return s;
}

// weight fetch: f32 mode rounds (RNE) to bf16; bf16 mode passes through
__device__ __forceinline__ u16 ldw(const void* base, size_t idx, int f32m){
  return f32m ? f2b(((const float*)base)[idx]) : ((const u16*)base)[idx];
}

__global__ void __launch_bounds__(TPB) lstm_init(u32* ws){
  int i = blockIdx.x * blockDim.x + threadIdx.x;
  if (i < WS_INIT_U32) ws[i] = 0u;   // zero flag + replica pair arrays (val=0, tag=0)
}

// dtype sniff: bf16 weights (|w| <= 2^-5) can never have a low-u16 bf16
// exponent field >= 144; f32 mantissa bits hit it with p~0.44 per sample.
__global__ void lstm_detect(const u32* __restrict__ wxg, u32* __restrict__ ws){
  if (threadIdx.x == 0 && blockIdx.x == 0){
    u32 f32m = 0;
    for (int i = 0; i < 128; ++i){
      u32 lo = wxg[i] & 0xffffu;
      u32 ef = (lo >> 7) & 0xffu;
      if (ef >= 144u) f32m = 1u;
    }
    ws[FLAG_IDX] = f32m;
  }
}

__global__ void __launch_bounds__(TPB) lstm_persist(
    const void* __restrict__ x,   const void* __restrict__ Wxg,
    const void* __restrict__ Whg, const void* __restrict__ bg,
    const void* __restrict__ Wcr, const void* __restrict__ Whr,
    const void* __restrict__ br,  void* __restrict__ out,
    u32* __restrict__ ws)
{
  extern __shared__ char smem[];
  const int tid  = threadIdx.x;
  const int b    = blockIdx.x;
  const int j0   = b * 4;            // this block owns h/c indices j0..j0+3
  const int w    = tid >> 6;         // wave id 0..3 ; wave w owns j = j0+w
  const int lane = tid & 63;

  const int f32m = (int)ws[FLAG_IDX];   // written by lstm_detect (kernel-boundary coherent)

  u32* ghp = ws + GHP_IDX;           // + r*2048 per replica
  u32* gcp = ws + GCP_IDX;
  u32* ghp_rd = ghp + (b & (NREP - 1)) * 2048;
  u32* gcp_rd = gcp + (b & (NREP - 1)) * 2048;

  u16*   wg   = (u16*)(smem + WG_OFF);
  u16*   whr  = (u16*)(smem + WHR_OFF);
  u16*   wcr  = (u16*)(smem + WCR_OFF);
  float* act  = (float*)(smem + ACT_OFF);
  float* hbuf = (float*)(smem + HBUF_OFF);
  float* cbuf = (float*)(smem + CBUF_OFF);

  // ---------- one-time weight staging into LDS ----------
  {
    // gate columns: col c = w*4 + q -> type q (o,f,i,g) of column j0 + w
    int c = tid >> 4, sub = tid & 15;
    int ty = c & 3, jl = c >> 2;
    size_t gcol = (size_t)(ty * HID + j0 + jl);
    u16* dst = wg + c * 1536;
    for (int k = sub * 96; k < sub * 96 + 96; ++k){
      u16 v = (k < KXDIM) ? ldw(Wxg, (size_t)k * 4096 + gcol, f32m)
                          : ldw(Whg, (size_t)(k - KXDIM) * 4096 + gcol, f32m);
      dst[k] = v;
    }
  }
  {
    // W_hr / W_cr columns, padded-chunk layout (24 u16 per 16 used)
    int jl = tid >> 6, sub = tid & 63;
    size_t j = (size_t)(j0 + jl);
    u16* dH = whr + jl * 1536 + sub * 24;
    u16* dC = wcr + jl * 1536 + sub * 24;
    for (int p = 0; p < 16; ++p){
      size_t k = (size_t)(sub * 16 + p);
      dH[p] = ldw(Whr, k * HID + j, f32m);
      dC[p] = ldw(Wcr, k * HID + j, f32m);
    }
  }
  // per-lane register constants: bg for (ty = lane&3, j = j0+w), br[j0+w]
  float bgv, brv;
  {
    size_t bidx = (size_t)((lane & 3) * HID + j0 + w);
    size_t ridx = (size_t)(j0 + w);
    bgv = f32m ? ((const float*)bg)[bidx] : bfs(((const u16*)bg)[bidx]);
    brv = f32m ? ((const float*)br)[ridx] : bfs(((const u16*)br)[ridx]);
  }
  float c_old = 0.0f;                // c state for j = j0+w (lane-replicated)
  __syncthreads();

  for (int t = 0; t < T_STEPS; ++t){
    // ---------- stage x_t into LDS (plain C loads: compiler inserts waitcnt) ----------
    {
      int e = tid * 2;                       // 0..510
      float f0, f1;
      if (f32m){
        const float* xr = (const float*)x + (size_t)t * KXDIM;
        f0 = xr[e]; f1 = xr[e + 1];
      } else {
        const u16* xr = (const u16*)x + (size_t)t * KXDIM;
        f0 = bfs(xr[e]); f1 = bfs(xr[e + 1]);
      }
      float* a = act + (e / 24) * 28 + (e % 24);
      a[0] = f0; a[1] = f1;
    }
    // ---------- h exchange: poll tagged pairs (tag == t), stage into LDS ----------
    {
      int k = tid * 4;                       // 0..1020
      float hv[4];
      poll4(ghp_rd, k, (u32)t, hv);
      int e = KXDIM + k;
      float* a = act + (e / 24) * 28 + (e % 24);
      a[0] = hv[0]; a[1] = hv[1]; a[2] = hv[2]; a[3] = hv[3];
      float* hb = hbuf + (k >> 4) * 20 + (k & 15);
      hb[0] = hv[0]; hb[1] = hv[1]; hb[2] = hv[2]; hb[3] = hv[3];
    }
    __syncthreads();                         // barrier 1: act/hbuf staged

    // ---------- gates: wave w computes all 4 gate types for its own j ----------
    float gact;
    {
      float a24[24];
      const float* av = act + lane * 28;
#pragma unroll
      for (int i2 = 0; i2 < 6; ++i2)
        *(float4*)(a24 + 4 * i2) = *(const float4*)(av + 4 * i2);

      float acc[4];
#pragma unroll
      for (int c2 = 0; c2 < 4; ++c2){
        const u32* wp = (const u32*)(wg + (4 * w + c2) * 1536) + lane * 12;
        u32 uu[12];
        *(uint4*)(uu + 0) = *(const uint4*)(wp + 0);
        *(uint4*)(uu + 4) = *(const uint4*)(wp + 4);
        *(uint4*)(uu + 8) = *(const uint4*)(wp + 8);
        float s2 = 0.f, s3 = 0.f;
#pragma unroll
        for (int p = 0; p < 12; ++p){
          s2 = fmaf(a24[2*p],     bflo(uu[p]), s2);
          s3 = fmaf(a24[2*p + 1], bfhi(uu[p]), s3);
        }
        acc[c2] = s2 + s3;
      }
      // folded reduction: lane class (lane&3)==q ends with full sum of acc[q]
#pragma unroll
      for (int c2 = 0; c2 < 4; ++c2){
        acc[c2] += __shfl_xor(acc[c2], 1, 64);
        acc[c2] += __shfl_xor(acc[c2], 2, 64);
      }
      float sel = (lane & 2) ? ((lane & 1) ? acc[3] : acc[2])
                             : ((lane & 1) ? acc[1] : acc[0]);
#pragma unroll
      for (int m = 4; m <= 32; m <<= 1) sel += __shfl_xor(sel, m, 64);
      // activation (all lanes): ty<3 sigmoid, ty==3 tanh via 2*sig(2g)-1
      int ty = lane & 3;
      float gv = sel + bgv;
      float sarg = (ty == 3) ? 2.0f * gv : gv;
      float sg = 1.0f / (1.0f + __expf(-sarg));
      gact = (ty == 3) ? 2.0f * sg - 1.0f : sg;
    }
    // assemble o,f,i,g from quad; update register c-state; publish c IMMEDIATELY
    int gbase = lane & ~3;
    float ov = __shfl(gact, gbase + 0, 64);
    float fv = __shfl(gact, gbase + 1, 64);
    float iv = __shfl(gact, gbase + 2, 64);
    float gg = __shfl(gact, gbase + 3, 64);
    float cn = fmaf(fv, c_old, iv * gg);
    c_old = cn;
    if (lane < 4) st_pair(gcp + lane * 2048, j0 + w, cn, (u32)(t + 1));

    // ---------- u = h . W_hr (own j) — overlaps c-store propagation ----------
    float ua = dot16(hbuf + lane * 20, (const u32*)(whr + w * 1536 + lane * 24));
#pragma unroll
    for (int m = 1; m <= 32; m <<= 1) ua += __shfl_xor(ua, m, 64);

    // ---------- c exchange: poll tagged pairs (tag == t+1), stage ----------
    {
      int k = tid * 4;
      float cv[4];
      poll4(gcp_rd, k, (u32)(t + 1), cv);
      float* cb = cbuf + (k >> 4) * 20 + (k & 15);
      cb[0] = cv[0]; cb[1] = cv[1]; cb[2] = cv[2]; cb[3] = cv[3];
    }
    __syncthreads();                         // barrier 2: cbuf staged

    // ---------- stage B: r = u + c_new.W_cr + b_r ; h_new = o*tanh(r) ----------
    {
      float ra = dot16(cbuf + lane * 20, (const u32*)(wcr + w * 1536 + lane * 24));
#pragma unroll
      for (int m = 1; m <= 32; m <<= 1) ra += __shfl_xor(ra, m, 64);
      float r  = ua + ra + brv;              // lane-uniform
      float hn = ov * tanhf(r);
      if (lane < 4) st_pair(ghp + lane * 2048, j0 + w, hn, (u32)(t + 1));
      if (lane == 4){
        if (f32m) ((float*)out)[(size_t)t * HID + j0 + w] = hn;
        else      ((u16*)out)[(size_t)t * HID + j0 + w] = f2b(hn);
      }
    }
    // no trailing barrier needed:
    //  - act/hbuf rewrite at t+1 happens after this block's h-poll(t+1)
    //    succeeds, which requires ALL blocks/waves to have finished stage B(t)
    //    (h published only at end of stage B) => no wave still reads act/hbuf.
    //  - cbuf rewrite at t+1 happens after barrier 1 of t+1, whose arrival
    //    requires every wave to have finished stage B(t)'s cbuf reads.
  }
}

extern "C" void kernel_launch(void* const* d_in, const int* in_sizes, int n_in,
                              void* d_out, int out_size, void* d_ws, size_t ws_size,
                              hipStream_t stream)
{
  const void* x   = d_in[0];
  const void* Wxg = d_in[1];
  const void* Whg = d_in[2];
  const void* bg  = d_in[3];
  const void* Wcr = d_in[4];   // NOTE: W_cr precedes W_hr in input order
  const void* Whr = d_in[5];
  const void* br  = d_in[6];
  u32* ws  = (u32*)d_ws;

  (void)in_sizes; (void)n_in; (void)out_size; (void)ws_size;

  lstm_init<<<dim3((WS_INIT_U32 + 255) / 256), dim3(256), 0, stream>>>(ws);
  lstm_detect<<<dim3(1), dim3(64), 0, stream>>>((const u32*)Wxg, ws);

  hipFuncSetAttribute((const void*)lstm_persist,
                      hipFuncAttributeMaxDynamicSharedMemorySize, SMEM_BYTES);
  lstm_persist<<<dim3(NBLK), dim3(TPB), SMEM_BYTES, stream>>>(
      x, Wxg, Whg, bg, Wcr, Whr, br, d_out, ws);
}